// Round 1
// baseline (327.237 us; speedup 1.0000x reference)
//
#include <hip/hip_runtime.h>
#include <hip/hip_bf16.h>
#include <math.h>

#define B_G   16
#define N_A   512
#define M_AT  8192
#define FD    128
#define HD    64
#define DD    16
#define SEIN  95
#define EHIN  159
#define NLUT  8192
#define DMAXF 140.0f

// ---------------------------------------------------------------- zero output
__global__ void k_zero(float* __restrict__ out) {
  if (threadIdx.x < B_G) out[threadIdx.x] = 0.f;
}

// ---------------------------------------------------------------- kernel LUT
// ker(d) = exp(-softplus(ks)*d)/max(d,1e-6) * (1 + tanh(MLP(rbf-features(d))))
// evaluated honestly from the input weights at NLUT grid points over [0,DMAX].
__global__ void k_lut(const float* __restrict__ k_screen,
                      const float* __restrict__ kg_w1, const float* __restrict__ kg_b1,
                      const float* __restrict__ kg_w2, const float* __restrict__ kg_b2,
                      float* __restrict__ lut) {
  int i = blockIdx.x * blockDim.x + threadIdx.x;
  if (i >= NLUT) return;
  float d = (float)i * (DMAXF / (float)(NLUT - 1));
  float ksv = k_screen[0];
  // stable softplus
  float screening = fmaxf(ksv, 0.f) + log1pf(expf(-fabsf(ksv)));
  float base = expf(-screening * d) / fmaxf(d, 1e-6f);
  float gin[10];
  gin[0] = d * (1.f / 5.0f);   // d/CUT
  gin[1] = d * (1.f / 40.0f);  // d/EMAX
#pragma unroll
  for (int kk = 0; kk < 8; ++kk) {        // centers linspace(5,40,8), gamma=1/25
    float u = d - (5.0f + 5.0f * (float)kk);
    gin[2 + kk] = expf(-(1.f / 25.f) * u * u);
  }
  float accv = 0.f;
  for (int h = 0; h < 32; ++h) {
    float z = kg_b1[h];
#pragma unroll
    for (int kk = 0; kk < 10; ++kk) z += gin[kk] * kg_w1[kk * 32 + h];
    float sl = z / (1.f + expf(-z));      // silu
    accv += sl * kg_w2[h];
  }
  accv += kg_b2[0];
  lut[i] = base * (1.f + tanhf(accv));
}

// ---------------------------------------------------------------- per-atom src
// 4 atoms per 512-thread block; sub-block of 128 threads per atom.
// LN(x,128) -> silu(128x64) -> 64x16 -> LN(16)
__global__ __launch_bounds__(512) void k_src(
    const float* __restrict__ x,
    const float* __restrict__ g, const float* __restrict__ bb,
    const float* __restrict__ w1, const float* __restrict__ b1,
    const float* __restrict__ w2, const float* __restrict__ b2,
    const float* __restrict__ lng, const float* __restrict__ lnb,
    float* __restrict__ srcout) {
  int t = threadIdx.x;
  int sb = t >> 7;          // sub-block (atom slot) 0..3
  int tt = t & 127;         // thread within sub-block
  int lane = t & 63;
  int hwid = tt >> 6;       // wave within sub-block
  int a = blockIdx.x * 4 + sb;

  __shared__ float xn[4][128];
  __shared__ float red[4][2];
  __shared__ float hpart[4][128];
  __shared__ float hbuf[4][64];
  __shared__ float sbuf[4][16];

  float v = x[(size_t)a * FD + tt];
  float s = v;
#pragma unroll
  for (int o = 32; o > 0; o >>= 1) s += __shfl_xor(s, o);
  if (lane == 0) red[sb][hwid] = s;
  __syncthreads();
  float m = (red[sb][0] + red[sb][1]) * (1.f / FD);
  float dv = v - m;
  float s2 = dv * dv;
#pragma unroll
  for (int o = 32; o > 0; o >>= 1) s2 += __shfl_xor(s2, o);
  __syncthreads();
  if (lane == 0) red[sb][hwid] = s2;
  __syncthreads();
  float var = (red[sb][0] + red[sb][1]) * (1.f / FD);
  xn[sb][tt] = dv * rsqrtf(var + 1e-5f) * g[tt] + bb[tt];
  __syncthreads();

  // hidden: 2 threads per hidden unit, each sums half the K range
  int j = tt & 63, half = tt >> 6;
  float acc = 0.f;
  const float* w1p = w1 + (size_t)(half * 64) * HD + j;
  const float* xp = &xn[sb][half * 64];
#pragma unroll 4
  for (int k = 0; k < 64; ++k) acc += xp[k] * w1p[(size_t)k * HD];
  hpart[sb][tt] = acc;
  __syncthreads();
  if (tt < 64) {
    float z = hpart[sb][tt] + hpart[sb][tt + 64] + b1[tt];
    hbuf[sb][tt] = z / (1.f + expf(-z));
  }
  __syncthreads();
  if (tt < 64) {  // full aligned wave
    int c = tt & 15, q = tt >> 4;
    float acc2 = 0.f;
    for (int k = q * 16; k < q * 16 + 16; ++k) acc2 += hbuf[sb][k] * w2[k * DD + c];
    acc2 += __shfl_down(acc2, 32);
    acc2 += __shfl_down(acc2, 16);
    if (tt < 16) sbuf[sb][tt] = acc2 + b2[tt];
  }
  __syncthreads();
  if (tt < 16) {
    float mm = 0.f;
#pragma unroll
    for (int k = 0; k < 16; ++k) mm += sbuf[sb][k];
    mm *= (1.f / 16.f);
    float vv = 0.f;
#pragma unroll
    for (int k = 0; k < 16; ++k) { float dd = sbuf[sb][k] - mm; vv += dd * dd; }
    vv *= (1.f / 16.f);
    srcout[(size_t)a * DD + tt] =
        (sbuf[sb][tt] - mm) * rsqrtf(vv + 1e-5f) * lng[tt] + lnb[tt];
  }
}

// ------------------------------------------------- graph-mean neutralization
__global__ __launch_bounds__(256) void k_center(float* __restrict__ src) {
  int gph = blockIdx.x, t = threadIdx.x;
  int c = t & 15, part = t >> 4;
  __shared__ float p[16][16];
  __shared__ float meanv[16];
  float accv = 0.f;
  for (int a2 = part; a2 < N_A; a2 += 16)
    accv += src[((size_t)gph * N_A + a2) * DD + c];
  p[part][c] = accv;
  __syncthreads();
  if (part == 0) {
    float sv = 0.f;
#pragma unroll
    for (int k = 0; k < 16; ++k) sv += p[k][c];
    meanv[c] = sv * (1.f / (float)N_A);   // max(cnt,1)=512
  }
  __syncthreads();
  float mv = meanv[c];
  for (int a2 = part; a2 < N_A; a2 += 16)
    src[((size_t)gph * N_A + a2) * DD + c] -= mv;
}

// ---------------------------------------------------------------- pair stage
// one wave per atom i; 4 atoms per 256-thread block; whole graph staged in LDS
__global__ __launch_bounds__(256) void k_pairs(
    const float* __restrict__ pos, const float* __restrict__ src,
    const float* __restrict__ lut, float* __restrict__ shell) {
  int gph = blockIdx.x >> 7;     // 128 blocks per graph
  int blk = blockIdx.x & 127;
  int t = threadIdx.x, wave = t >> 6, lane = t & 63;
  int i_local = blk * 4 + wave;

  __shared__ float sp[N_A * 3];
  __shared__ float ss[N_A * DD];
  __shared__ float wb[4][N_A];
  __shared__ unsigned char tbs[4][N_A];

  for (int idx = t; idx < N_A * 3; idx += 256) sp[idx] = pos[(size_t)gph * N_A * 3 + idx];
  for (int idx = t; idx < N_A * DD; idx += 256) ss[idx] = src[(size_t)gph * N_A * DD + idx];
  __syncthreads();

  float px = sp[i_local * 3], py = sp[i_local * 3 + 1], pz = sp[i_local * 3 + 2];
  float cnt[5] = {0, 0, 0, 0, 0}, sd[5] = {0, 0, 0, 0, 0}, sdd[5] = {0, 0, 0, 0, 0};
  const float lscale = (float)(NLUT - 1) / DMAXF;

  // phase 1: each lane handles 8 j's
#pragma unroll
  for (int it = 0; it < 8; ++it) {
    int jv = lane + it * 64;
    float dx = px - sp[jv * 3], dy = py - sp[jv * 3 + 1], dz = pz - sp[jv * 3 + 2];
    float d2 = dx * dx + dy * dy + dz * dz + 1e-12f;
    float d = sqrtf(d2);
    bool valid = (jv != i_local) && (d >= 5.0f);
    int tq = (d >= 10.f) + (d >= 20.f) + (d >= 40.f) + (d >= 80.f);  // shell 0..4 (for d>=5)
    float xq = d * lscale;
    int i0 = (int)xq; i0 = min(i0, NLUT - 2);
    float f = xq - (float)i0;
    float l0 = lut[i0], l1 = lut[i0 + 1];
    float w = valid ? (l0 + (l1 - l0) * f) : 0.f;
    wb[wave][jv] = w;
    tbs[wave][jv] = (unsigned char)tq;
    float dm = valid ? d : 0.f;
    float ddm = valid ? d * d : 0.f;
    float cm = valid ? 1.f : 0.f;
#pragma unroll
    for (int q = 0; q < 5; ++q) {
      bool mq = (tq == q);
      cnt[q] += mq ? cm : 0.f;
      sd[q]  += mq ? dm : 0.f;
      sdd[q] += mq ? ddm : 0.f;
    }
  }
  // wave totals for scalar stats (butterfly: all lanes get totals)
#pragma unroll
  for (int q = 0; q < 5; ++q) {
#pragma unroll
    for (int o = 32; o > 0; o >>= 1) {
      cnt[q] += __shfl_xor(cnt[q], o);
      sd[q]  += __shfl_xor(sd[q], o);
      sdd[q] += __shfl_xor(sdd[q], o);
    }
  }
  __syncthreads();

  // phase 2: lane -> (dim c, j-chunk); interleaved j keeps ss reads conflict-free
  int c = lane & 15, chunk = lane >> 4;
  float acc[5] = {0, 0, 0, 0, 0};
  for (int jj = 0; jj < 128; ++jj) {
    int jv = jj * 4 + chunk;                 // ss addr = 64*jj + lane (conflict-free)
    float w = wb[wave][jv];
    int tq = tbs[wave][jv];
    float wsv = w * ss[jv * DD + c];
    acc[0] += (tq == 0) ? wsv : 0.f;
    acc[1] += (tq == 1) ? wsv : 0.f;
    acc[2] += (tq == 2) ? wsv : 0.f;
    acc[3] += (tq == 3) ? wsv : 0.f;
    acc[4] += (tq == 4) ? wsv : 0.f;
  }
#pragma unroll
  for (int q = 0; q < 5; ++q) {
    acc[q] += __shfl_down(acc[q], 32);
    acc[q] += __shfl_down(acc[q], 16);
  }

  float* shp = shell + (size_t)(gph * N_A + i_local) * SEIN;
  if (lane < 16) {
#pragma unroll
    for (int q = 0; q < 5; ++q) shp[q * 19 + lane] = acc[q] / fmaxf(cnt[q], 1.f);
  }
  if (lane < 5) {
    int q = lane;
    float denom = fmaxf(cnt[q], 1.f);
    shp[q * 19 + 16] = cnt[q];
    shp[q * 19 + 17] = sd[q] / denom;
    shp[q * 19 + 18] = sqrtf(sdd[q] / denom + 1e-12f);
  }
}

// ---------------------------------------------------------------- tail MLPs
// one wave per atom; 4 atoms per 256-thread block
__global__ __launch_bounds__(256) void k_tail(
    const float* __restrict__ src, const float* __restrict__ shell,
    const float* __restrict__ se_ln_g, const float* __restrict__ se_ln_b,
    const float* __restrict__ se_w1, const float* __restrict__ se_b1,
    const float* __restrict__ se_w2, const float* __restrict__ se_b2,
    const float* __restrict__ eh_ln_g, const float* __restrict__ eh_ln_b,
    const float* __restrict__ eh_w1, const float* __restrict__ eh_b1,
    const float* __restrict__ eh_w2, const float* __restrict__ eh_b2,
    const float* __restrict__ far_gate, const float* __restrict__ energy_scale,
    float* __restrict__ out) {
  int t = threadIdx.x, w = t >> 6, lane = t & 63;
  int a = blockIdx.x * 4 + w;
  int gph = a >> 9;   // 512 atoms per graph
  const float* sh = shell + (size_t)a * SEIN;

  __shared__ float shn[4][SEIN];
  __shared__ float hb[4][HD];
  __shared__ float einn[4][EHIN];
  __shared__ float embS[4][DD];

  // LN(shell, 95)
  float s1 = 0.f;
  for (int k = lane; k < SEIN; k += 64) s1 += sh[k];
#pragma unroll
  for (int o = 32; o > 0; o >>= 1) s1 += __shfl_xor(s1, o);
  float m = s1 * (1.f / (float)SEIN);
  float s2 = 0.f;
  for (int k = lane; k < SEIN; k += 64) { float dd = sh[k] - m; s2 += dd * dd; }
#pragma unroll
  for (int o = 32; o > 0; o >>= 1) s2 += __shfl_xor(s2, o);
  float inv = rsqrtf(s2 * (1.f / (float)SEIN) + 1e-5f);
  for (int k = lane; k < SEIN; k += 64)
    shn[w][k] = (sh[k] - m) * inv * se_ln_g[k] + se_ln_b[k];
  __syncthreads();

  // se hidden (95 -> 64), silu
  float z = se_b1[lane];
  for (int k = 0; k < SEIN; ++k) z += shn[w][k] * se_w1[k * HD + lane];
  hb[w][lane] = z / (1.f + expf(-z));
  __syncthreads();

  // emb (64 -> 16)
  int c = lane & 15, q = lane >> 4;
  float e = 0.f;
  for (int k = q * 16; k < q * 16 + 16; ++k) e += hb[w][k] * se_w2[k * DD + c];
  e += __shfl_down(e, 32);
  e += __shfl_down(e, 16);
  if (lane < 16) embS[w][lane] = e + se_b2[lane];
  __syncthreads();

  // build ein = [src, emb, src*emb, src-emb, shell]
  const float* sr = src + (size_t)a * DD;
  if (lane < 16) {
    float sv = sr[lane], ev = embS[w][lane];
    einn[w][lane] = sv;
    einn[w][16 + lane] = ev;
    einn[w][32 + lane] = sv * ev;
    einn[w][48 + lane] = sv - ev;
  }
  for (int k = lane; k < SEIN; k += 64) einn[w][64 + k] = sh[k];
  __syncthreads();

  // LN(ein, 159)
  float t1 = 0.f;
  for (int k = lane; k < EHIN; k += 64) t1 += einn[w][k];
#pragma unroll
  for (int o = 32; o > 0; o >>= 1) t1 += __shfl_xor(t1, o);
  float m2 = t1 * (1.f / (float)EHIN);
  float t2 = 0.f;
  for (int k = lane; k < EHIN; k += 64) { float dd = einn[w][k] - m2; t2 += dd * dd; }
#pragma unroll
  for (int o = 32; o > 0; o >>= 1) t2 += __shfl_xor(t2, o);
  float inv2 = rsqrtf(t2 * (1.f / (float)EHIN) + 1e-5f);
  __syncthreads();
  for (int k = lane; k < EHIN; k += 64)
    einn[w][k] = (einn[w][k] - m2) * inv2 * eh_ln_g[k] + eh_ln_b[k];
  __syncthreads();

  // eh hidden (159 -> 64), silu, dot with eh_w2 (64 -> 1)
  float z2 = eh_b1[lane];
  for (int k = 0; k < EHIN; ++k) z2 += einn[w][k] * eh_w1[k * HD + lane];
  float h2 = z2 / (1.f + expf(-z2));
  float contrib = h2 * eh_w2[lane];
#pragma unroll
  for (int o = 32; o > 0; o >>= 1) contrib += __shfl_xor(contrib, o);
  if (lane == 0) {
    float pa = (contrib + eh_b2[0]) * tanhf(far_gate[0]) * expf(energy_scale[0]);
    atomicAdd(&out[gph], pa);
  }
}

// ---------------------------------------------------------------- launch
extern "C" void kernel_launch(void* const* d_in, const int* in_sizes, int n_in,
                              void* d_out, int out_size, void* d_ws, size_t ws_size,
                              hipStream_t stream) {
  const float* x         = (const float*)d_in[0];
  const float* pos       = (const float*)d_in[1];
  // d_in[2]=batch (int32), d_in[3]=num_graphs — layout is g*512+a by construction
  const float* in_ln_g   = (const float*)d_in[4];
  const float* in_ln_b   = (const float*)d_in[5];
  const float* src_w1    = (const float*)d_in[6];
  const float* src_b1    = (const float*)d_in[7];
  const float* src_w2    = (const float*)d_in[8];
  const float* src_b2    = (const float*)d_in[9];
  const float* src_ln_g  = (const float*)d_in[10];
  const float* src_ln_b  = (const float*)d_in[11];
  const float* se_ln_g   = (const float*)d_in[12];
  const float* se_ln_b   = (const float*)d_in[13];
  const float* se_w1     = (const float*)d_in[14];
  const float* se_b1     = (const float*)d_in[15];
  const float* se_w2     = (const float*)d_in[16];
  const float* se_b2     = (const float*)d_in[17];
  const float* eh_ln_g   = (const float*)d_in[18];
  const float* eh_ln_b   = (const float*)d_in[19];
  const float* eh_w1     = (const float*)d_in[20];
  const float* eh_b1     = (const float*)d_in[21];
  const float* eh_w2     = (const float*)d_in[22];
  const float* eh_b2     = (const float*)d_in[23];
  const float* k_screen  = (const float*)d_in[24];
  const float* kg_w1     = (const float*)d_in[25];
  const float* kg_b1     = (const float*)d_in[26];
  const float* kg_w2     = (const float*)d_in[27];
  const float* kg_b2     = (const float*)d_in[28];
  const float* far_gate  = (const float*)d_in[29];
  const float* en_scale  = (const float*)d_in[30];
  float* out = (float*)d_out;

  float* ws_src   = (float*)d_ws;                      // M*16
  float* ws_shell = ws_src + (size_t)M_AT * DD;        // M*95
  float* ws_lut   = ws_shell + (size_t)M_AT * SEIN;    // NLUT

  k_zero<<<1, 64, 0, stream>>>(out);
  k_lut<<<NLUT / 256, 256, 0, stream>>>(k_screen, kg_w1, kg_b1, kg_w2, kg_b2, ws_lut);
  k_src<<<M_AT / 4, 512, 0, stream>>>(x, in_ln_g, in_ln_b, src_w1, src_b1,
                                      src_w2, src_b2, src_ln_g, src_ln_b, ws_src);
  k_center<<<B_G, 256, 0, stream>>>(ws_src);
  k_pairs<<<B_G * (N_A / 4), 256, 0, stream>>>(pos, ws_src, ws_lut, ws_shell);
  k_tail<<<M_AT / 4, 256, 0, stream>>>(ws_src, ws_shell,
                                       se_ln_g, se_ln_b, se_w1, se_b1, se_w2, se_b2,
                                       eh_ln_g, eh_ln_b, eh_w1, eh_b1, eh_w2, eh_b2,
                                       far_gate, en_scale, out);
}

// Round 2
// 258.890 us; speedup vs baseline: 1.2640x; 1.2640x over previous
//
#include <hip/hip_runtime.h>
#include <hip/hip_bf16.h>
#include <math.h>

#define B_G   16
#define N_A   512
#define M_AT  8192
#define FD    128
#define HD    64
#define DD    16
#define SEIN  95
#define EHIN  159
#define NLUT  1024
#define DMAXF 140.0f

// ---------------------------------------------------------------- zero output
__global__ void k_zero(float* __restrict__ out) {
  if (threadIdx.x < B_G) out[threadIdx.x] = 0.f;
}

// ---------------------------------------------------------------- kernel LUT
// lut[i] = (ker(d_i), ker(d_{i+1})-ker(d_i)) for linear interp with one b64 read.
// ker(d) = exp(-softplus(ks)*d)/max(d,1e-6) * (1 + tanh(MLP(rbf(d))))
__global__ void k_lut2(const float* __restrict__ k_screen,
                       const float* __restrict__ kg_w1, const float* __restrict__ kg_b1,
                       const float* __restrict__ kg_w2, const float* __restrict__ kg_b2,
                       float2* __restrict__ lut) {
  int i = blockIdx.x * blockDim.x + threadIdx.x;
  if (i >= NLUT) return;
  float step = DMAXF / (float)(NLUT - 1);
  float ksv = k_screen[0];
  float screening = fmaxf(ksv, 0.f) + log1pf(expf(-fabsf(ksv)));
  float vals[2];
#pragma unroll
  for (int e = 0; e < 2; ++e) {
    int ii = min(i + e, NLUT - 1);
    float d = (float)ii * step;
    float base = expf(-screening * d) / fmaxf(d, 1e-6f);
    float gin[10];
    gin[0] = d * (1.f / 5.0f);
    gin[1] = d * (1.f / 40.0f);
#pragma unroll
    for (int kk = 0; kk < 8; ++kk) {
      float u = d - (5.0f + 5.0f * (float)kk);
      gin[2 + kk] = expf(-(1.f / 25.f) * u * u);
    }
    float accv = 0.f;
    for (int h = 0; h < 32; ++h) {
      float z = kg_b1[h];
#pragma unroll
      for (int kk = 0; kk < 10; ++kk) z += gin[kk] * kg_w1[kk * 32 + h];
      accv += (z / (1.f + expf(-z))) * kg_w2[h];
    }
    accv += kg_b2[0];
    vals[e] = base * (1.f + tanhf(accv));
  }
  lut[i] = make_float2(vals[0], vals[1] - vals[0]);
}

// ---------------------------------------------------------------- per-atom src
// 16 atoms/block (4 waves x 4 atoms); weights staged in LDS.
__global__ __launch_bounds__(256) void k_src(
    const float* __restrict__ x,
    const float* __restrict__ g, const float* __restrict__ bb,
    const float* __restrict__ w1, const float* __restrict__ b1,
    const float* __restrict__ w2, const float* __restrict__ b2,
    const float* __restrict__ lng, const float* __restrict__ lnb,
    float* __restrict__ srcout) {
  int t = threadIdx.x, wave = t >> 6, lane = t & 63;

  __shared__ __align__(16) float w1s[FD * HD];   // 32 KB
  __shared__ __align__(16) float w2s[HD * DD];   // 4 KB
  __shared__ float xns[4][FD];
  __shared__ float hbs[4][HD];

#pragma unroll
  for (int idx = t; idx < FD * HD / 4; idx += 256)
    ((float4*)w1s)[idx] = ((const float4*)w1)[idx];
  ((float4*)w2s)[t] = ((const float4*)w2)[t];  // 256 float4 exactly
  __syncthreads();

  for (int aa = 0; aa < 4; ++aa) {
    int a = blockIdx.x * 16 + wave * 4 + aa;
    const float* xp = x + (size_t)a * FD;
    float v0 = xp[lane], v1 = xp[lane + 64];
    float s = v0 + v1;
#pragma unroll
    for (int o = 32; o > 0; o >>= 1) s += __shfl_xor(s, o);
    float m = s * (1.f / FD);
    float d0 = v0 - m, d1 = v1 - m;
    float s2 = d0 * d0 + d1 * d1;
#pragma unroll
    for (int o = 32; o > 0; o >>= 1) s2 += __shfl_xor(s2, o);
    float inv = rsqrtf(s2 * (1.f / FD) + 1e-5f);
    xns[wave][lane] = d0 * inv * g[lane] + bb[lane];
    xns[wave][lane + 64] = d1 * inv * g[lane + 64] + bb[lane + 64];
    __syncthreads();

    float z = b1[lane];
#pragma unroll 8
    for (int k = 0; k < FD; ++k) z += xns[wave][k] * w1s[k * HD + lane];
    hbs[wave][lane] = z / (1.f + expf(-z));
    __syncthreads();

    int c = lane & 15, q = lane >> 4;
    float acc2 = 0.f;
#pragma unroll
    for (int kk = 0; kk < 16; ++kk) {
      int k = q * 16 + kk;
      acc2 += hbs[wave][k] * w2s[k * DD + c];
    }
    acc2 += __shfl_down(acc2, 32);
    acc2 += __shfl_down(acc2, 16);
    float sval = acc2 + b2[c];          // valid on lanes 0..15
    float ssum = sval;
#pragma unroll
    for (int o = 8; o > 0; o >>= 1) ssum += __shfl_xor(ssum, o);
    float mm = ssum * (1.f / 16.f);
    float dv = sval - mm;
    float vv = dv * dv;
#pragma unroll
    for (int o = 8; o > 0; o >>= 1) vv += __shfl_xor(vv, o);
    if (lane < 16)
      srcout[(size_t)a * DD + lane] =
          dv * rsqrtf(vv * (1.f / 16.f) + 1e-5f) * lng[lane] + lnb[lane];
    __syncthreads();
  }
}

// ------------------------------------------------- graph-mean neutralization
__global__ __launch_bounds__(256) void k_center(float* __restrict__ src) {
  int gph = blockIdx.x, t = threadIdx.x;
  int c = t & 15, part = t >> 4;
  __shared__ float p[16][16];
  __shared__ float meanv[16];
  float accv = 0.f;
  for (int a2 = part; a2 < N_A; a2 += 16)
    accv += src[((size_t)gph * N_A + a2) * DD + c];
  p[part][c] = accv;
  __syncthreads();
  if (part == 0) {
    float sv = 0.f;
#pragma unroll
    for (int k = 0; k < 16; ++k) sv += p[k][c];
    meanv[c] = sv * (1.f / (float)N_A);
  }
  __syncthreads();
  float mv = meanv[c];
  for (int a2 = part; a2 < N_A; a2 += 16)
    src[((size_t)gph * N_A + a2) * DD + c] -= mv;
}

// ---------------------------------------------------------------- pair stage
// one wave per atom i; 4 atoms per 256-thread block; graph + LUT staged in LDS
__global__ __launch_bounds__(256) void k_pairs(
    const float* __restrict__ pos, const float* __restrict__ src,
    const float2* __restrict__ lut, float* __restrict__ shell) {
  int gph = blockIdx.x >> 7;
  int blk = blockIdx.x & 127;
  int t = threadIdx.x, wave = t >> 6, lane = t & 63;
  int i_local = blk * 4 + wave;

  __shared__ __align__(16) float sp[N_A * 3];        // 6 KB
  __shared__ __align__(16) float ss[N_A * DD];       // 32 KB
  __shared__ __align__(16) float2 luts[NLUT];        // 8 KB
  __shared__ float wb[4][N_A];                       // 8 KB
  __shared__ unsigned char tbs[4][N_A];              // 2 KB

#pragma unroll
  for (int idx = t; idx < N_A * 3 / 4; idx += 256)
    ((float4*)sp)[idx] = ((const float4*)(pos + (size_t)gph * N_A * 3))[idx];
#pragma unroll
  for (int idx = t; idx < N_A * DD / 4; idx += 256)
    ((float4*)ss)[idx] = ((const float4*)(src + (size_t)gph * N_A * DD))[idx];
#pragma unroll
  for (int idx = t; idx < NLUT / 2; idx += 256)
    ((float4*)luts)[idx] = ((const float4*)lut)[idx];
  __syncthreads();

  float px = sp[i_local * 3], py = sp[i_local * 3 + 1], pz = sp[i_local * 3 + 2];
  float cnt[5] = {0, 0, 0, 0, 0}, sd[5] = {0, 0, 0, 0, 0}, sdd[5] = {0, 0, 0, 0, 0};
  const float lscale = (float)(NLUT - 1) / DMAXF;

#pragma unroll
  for (int it = 0; it < 8; ++it) {
    int jv = lane + it * 64;
    float dx = px - sp[jv * 3], dy = py - sp[jv * 3 + 1], dz = pz - sp[jv * 3 + 2];
    float d2 = dx * dx + dy * dy + dz * dz + 1e-12f;
    float d = sqrtf(d2);
    bool valid = (jv != i_local) && (d >= 5.0f);
    int tq = (d >= 10.f) + (d >= 20.f) + (d >= 40.f) + (d >= 80.f);
    float xq = d * lscale;
    int i0 = min((int)xq, NLUT - 2);
    float f = xq - (float)i0;
    float2 L = luts[i0];
    float w = valid ? (L.x + L.y * f) : 0.f;
    wb[wave][jv] = w;
    tbs[wave][jv] = (unsigned char)tq;
    float dm = valid ? d : 0.f;
    float ddm = valid ? d * d : 0.f;
    float cm = valid ? 1.f : 0.f;
#pragma unroll
    for (int q = 0; q < 5; ++q) {
      bool mq = (tq == q);
      cnt[q] += mq ? cm : 0.f;
      sd[q]  += mq ? dm : 0.f;
      sdd[q] += mq ? ddm : 0.f;
    }
  }
#pragma unroll
  for (int q = 0; q < 5; ++q) {
#pragma unroll
    for (int o = 32; o > 0; o >>= 1) {
      cnt[q] += __shfl_xor(cnt[q], o);
      sd[q]  += __shfl_xor(sd[q], o);
      sdd[q] += __shfl_xor(sdd[q], o);
    }
  }
  __syncthreads();

  // phase 2: lane -> (dim c, chunk); ss addr = 64*jj + lane (conflict-free)
  int c = lane & 15, chunk = lane >> 4;
  float acc[5] = {0, 0, 0, 0, 0};
  for (int jj = 0; jj < 128; ++jj) {
    int jv = jj * 4 + chunk;
    float w = wb[wave][jv];
    int tq = tbs[wave][jv];
    float wsv = w * ss[jv * DD + c];
    acc[0] += (tq == 0) ? wsv : 0.f;
    acc[1] += (tq == 1) ? wsv : 0.f;
    acc[2] += (tq == 2) ? wsv : 0.f;
    acc[3] += (tq == 3) ? wsv : 0.f;
    acc[4] += (tq == 4) ? wsv : 0.f;
  }
#pragma unroll
  for (int q = 0; q < 5; ++q) {
    acc[q] += __shfl_down(acc[q], 32);
    acc[q] += __shfl_down(acc[q], 16);
  }

  float* shp = shell + (size_t)(gph * N_A + i_local) * SEIN;
  if (lane < 16) {
#pragma unroll
    for (int q = 0; q < 5; ++q) shp[q * 19 + lane] = acc[q] / fmaxf(cnt[q], 1.f);
  }
  if (lane < 5) {
    int q = lane;
    float denom = fmaxf(cnt[q], 1.f);
    shp[q * 19 + 16] = cnt[q];
    shp[q * 19 + 17] = sd[q] / denom;
    shp[q * 19 + 18] = sqrtf(sdd[q] / denom + 1e-12f);
  }
}

// ---------------------------------------------------------------- tail A: emb
// 16 atoms/block; se weights staged in LDS; writes emb[M,16]
__global__ __launch_bounds__(256) void k_tail_a(
    const float* __restrict__ shell,
    const float* __restrict__ se_ln_g, const float* __restrict__ se_ln_b,
    const float* __restrict__ se_w1, const float* __restrict__ se_b1,
    const float* __restrict__ se_w2, const float* __restrict__ se_b2,
    float* __restrict__ emb) {
  int t = threadIdx.x, wave = t >> 6, lane = t & 63;

  __shared__ __align__(16) float w1s[SEIN * HD];   // 24,320 B
  __shared__ __align__(16) float w2s[HD * DD];     // 4 KB
  __shared__ float shns[4][SEIN];
  __shared__ float hbs[4][HD];

  for (int idx = t; idx < SEIN * HD / 4; idx += 256)
    ((float4*)w1s)[idx] = ((const float4*)se_w1)[idx];
  ((float4*)w2s)[t] = ((const float4*)se_w2)[t];
  __syncthreads();

  for (int aa = 0; aa < 4; ++aa) {
    int a = blockIdx.x * 16 + wave * 4 + aa;
    const float* sh = shell + (size_t)a * SEIN;
    float s1 = 0.f;
    for (int k = lane; k < SEIN; k += 64) s1 += sh[k];
#pragma unroll
    for (int o = 32; o > 0; o >>= 1) s1 += __shfl_xor(s1, o);
    float m = s1 * (1.f / (float)SEIN);
    float s2 = 0.f;
    for (int k = lane; k < SEIN; k += 64) { float dd = sh[k] - m; s2 += dd * dd; }
#pragma unroll
    for (int o = 32; o > 0; o >>= 1) s2 += __shfl_xor(s2, o);
    float inv = rsqrtf(s2 * (1.f / (float)SEIN) + 1e-5f);
    for (int k = lane; k < SEIN; k += 64)
      shns[wave][k] = (sh[k] - m) * inv * se_ln_g[k] + se_ln_b[k];
    __syncthreads();

    float z = se_b1[lane];
#pragma unroll 5
    for (int k = 0; k < SEIN; ++k) z += shns[wave][k] * w1s[k * HD + lane];
    hbs[wave][lane] = z / (1.f + expf(-z));
    __syncthreads();

    int c = lane & 15, q = lane >> 4;
    float e = 0.f;
#pragma unroll
    for (int kk = 0; kk < 16; ++kk) {
      int k = q * 16 + kk;
      e += hbs[wave][k] * w2s[k * DD + c];
    }
    e += __shfl_down(e, 32);
    e += __shfl_down(e, 16);
    if (lane < 16) emb[(size_t)a * DD + lane] = e + se_b2[lane];
    __syncthreads();
  }
}

// ---------------------------------------------------------------- tail B: energy
// 16 atoms/block (same graph); eh weights staged; block-reduced atomic
__global__ __launch_bounds__(256) void k_tail_b(
    const float* __restrict__ src, const float* __restrict__ emb,
    const float* __restrict__ shell,
    const float* __restrict__ eh_ln_g, const float* __restrict__ eh_ln_b,
    const float* __restrict__ eh_w1, const float* __restrict__ eh_b1,
    const float* __restrict__ eh_w2, const float* __restrict__ eh_b2,
    const float* __restrict__ far_gate, const float* __restrict__ energy_scale,
    float* __restrict__ out) {
  int t = threadIdx.x, wave = t >> 6, lane = t & 63;
  int a0 = blockIdx.x * 16;
  int gph = a0 >> 9;

  __shared__ __align__(16) float w1s[EHIN * HD];   // 40,704 B
  __shared__ float einns[4][EHIN];
  __shared__ float red[4];

  for (int idx = t; idx < EHIN * HD / 4; idx += 256)
    ((float4*)w1s)[idx] = ((const float4*)eh_w1)[idx];
  __syncthreads();

  float pa_acc = 0.f;
  for (int aa = 0; aa < 4; ++aa) {
    int a = a0 + wave * 4 + aa;
    const float* sh = shell + (size_t)a * SEIN;
    if (lane < 16) {
      float sv = src[(size_t)a * DD + lane], ev = emb[(size_t)a * DD + lane];
      einns[wave][lane] = sv;
      einns[wave][16 + lane] = ev;
      einns[wave][32 + lane] = sv * ev;
      einns[wave][48 + lane] = sv - ev;
    }
    for (int k = lane; k < SEIN; k += 64) einns[wave][64 + k] = sh[k];
    __syncthreads();

    float t1 = 0.f;
    for (int k = lane; k < EHIN; k += 64) t1 += einns[wave][k];
#pragma unroll
    for (int o = 32; o > 0; o >>= 1) t1 += __shfl_xor(t1, o);
    float m2 = t1 * (1.f / (float)EHIN);
    float t2 = 0.f;
    for (int k = lane; k < EHIN; k += 64) { float dd = einns[wave][k] - m2; t2 += dd * dd; }
#pragma unroll
    for (int o = 32; o > 0; o >>= 1) t2 += __shfl_xor(t2, o);
    float inv2 = rsqrtf(t2 * (1.f / (float)EHIN) + 1e-5f);
    for (int k = lane; k < EHIN; k += 64)
      einns[wave][k] = (einns[wave][k] - m2) * inv2 * eh_ln_g[k] + eh_ln_b[k];
    __syncthreads();

    float z2 = eh_b1[lane];
#pragma unroll 4
    for (int k = 0; k < EHIN; ++k) z2 += einns[wave][k] * w1s[k * HD + lane];
    float h2 = z2 / (1.f + expf(-z2));
    float contrib = h2 * eh_w2[lane];
#pragma unroll
    for (int o = 32; o > 0; o >>= 1) contrib += __shfl_xor(contrib, o);
    pa_acc += contrib + eh_b2[0];
    __syncthreads();
  }
  if (lane == 0) red[wave] = pa_acc;
  __syncthreads();
  if (t == 0) {
    float tot = red[0] + red[1] + red[2] + red[3];
    atomicAdd(&out[gph], tot * tanhf(far_gate[0]) * expf(energy_scale[0]));
  }
}

// ---------------------------------------------------------------- launch
extern "C" void kernel_launch(void* const* d_in, const int* in_sizes, int n_in,
                              void* d_out, int out_size, void* d_ws, size_t ws_size,
                              hipStream_t stream) {
  const float* x         = (const float*)d_in[0];
  const float* pos       = (const float*)d_in[1];
  const float* in_ln_g   = (const float*)d_in[4];
  const float* in_ln_b   = (const float*)d_in[5];
  const float* src_w1    = (const float*)d_in[6];
  const float* src_b1    = (const float*)d_in[7];
  const float* src_w2    = (const float*)d_in[8];
  const float* src_b2    = (const float*)d_in[9];
  const float* src_ln_g  = (const float*)d_in[10];
  const float* src_ln_b  = (const float*)d_in[11];
  const float* se_ln_g   = (const float*)d_in[12];
  const float* se_ln_b   = (const float*)d_in[13];
  const float* se_w1     = (const float*)d_in[14];
  const float* se_b1     = (const float*)d_in[15];
  const float* se_w2     = (const float*)d_in[16];
  const float* se_b2     = (const float*)d_in[17];
  const float* eh_ln_g   = (const float*)d_in[18];
  const float* eh_ln_b   = (const float*)d_in[19];
  const float* eh_w1     = (const float*)d_in[20];
  const float* eh_b1     = (const float*)d_in[21];
  const float* eh_w2     = (const float*)d_in[22];
  const float* eh_b2     = (const float*)d_in[23];
  const float* k_screen  = (const float*)d_in[24];
  const float* kg_w1     = (const float*)d_in[25];
  const float* kg_b1     = (const float*)d_in[26];
  const float* kg_w2     = (const float*)d_in[27];
  const float* kg_b2     = (const float*)d_in[28];
  const float* far_gate  = (const float*)d_in[29];
  const float* en_scale  = (const float*)d_in[30];
  float* out = (float*)d_out;

  float* ws_src   = (float*)d_ws;                      // M*16
  float* ws_shell = ws_src + (size_t)M_AT * DD;        // M*95
  float* ws_emb   = ws_shell + (size_t)M_AT * SEIN;    // M*16
  float2* ws_lut  = (float2*)(ws_emb + (size_t)M_AT * DD);  // NLUT float2

  k_zero<<<1, 64, 0, stream>>>(out);
  k_lut2<<<NLUT / 256, 256, 0, stream>>>(k_screen, kg_w1, kg_b1, kg_w2, kg_b2, ws_lut);
  k_src<<<M_AT / 16, 256, 0, stream>>>(x, in_ln_g, in_ln_b, src_w1, src_b1,
                                       src_w2, src_b2, src_ln_g, src_ln_b, ws_src);
  k_center<<<B_G, 256, 0, stream>>>(ws_src);
  k_pairs<<<B_G * (N_A / 4), 256, 0, stream>>>(pos, ws_src, ws_lut, ws_shell);
  k_tail_a<<<M_AT / 16, 256, 0, stream>>>(ws_shell, se_ln_g, se_ln_b,
                                          se_w1, se_b1, se_w2, se_b2, ws_emb);
  k_tail_b<<<M_AT / 16, 256, 0, stream>>>(ws_src, ws_emb, ws_shell,
                                          eh_ln_g, eh_ln_b, eh_w1, eh_b1, eh_w2, eh_b2,
                                          far_gate, en_scale, out);
}

// Round 3
// 220.963 us; speedup vs baseline: 1.4810x; 1.1716x over previous
//
#include <hip/hip_runtime.h>
#include <hip/hip_bf16.h>
#include <math.h>

#define B_G   16
#define N_A   512
#define M_AT  8192
#define FD    128
#define HD    64
#define DD    16
#define SEIN  95
#define EHIN  159
#define NLUT  1024
#define DMAXF 140.0f

__device__ __forceinline__ float silu_f(float z) { return z / (1.f + __expf(-z)); }

// ---------------------------------------------------------------- kernel LUT (+ zero out)
__global__ __launch_bounds__(256) void k_lut2(
    const float* __restrict__ k_screen,
    const float* __restrict__ kg_w1, const float* __restrict__ kg_b1,
    const float* __restrict__ kg_w2, const float* __restrict__ kg_b2,
    float2* __restrict__ lut, float* __restrict__ out) {
  int t = threadIdx.x;
  if (blockIdx.x == 0 && t < B_G) out[t] = 0.f;

  __shared__ float w1l[320], b1l[32], w2l[32];
  for (int idx = t; idx < 320; idx += 256) w1l[idx] = kg_w1[idx];
  if (t < 32) { b1l[t] = kg_b1[t]; w2l[t] = kg_w2[t]; }
  __syncthreads();

  int i = blockIdx.x * 256 + t;
  if (i >= NLUT) return;
  float step = DMAXF / (float)(NLUT - 1);
  float ksv = k_screen[0];
  float screening = fmaxf(ksv, 0.f) + log1pf(expf(-fabsf(ksv)));
  float b2v = kg_b2[0];
  float vals[2];
#pragma unroll
  for (int e = 0; e < 2; ++e) {
    int ii = min(i + e, NLUT - 1);
    float d = (float)ii * step;
    float base = expf(-screening * d) / fmaxf(d, 1e-6f);
    float gin[10];
    gin[0] = d * (1.f / 5.0f);
    gin[1] = d * (1.f / 40.0f);
#pragma unroll
    for (int kk = 0; kk < 8; ++kk) {
      float u = d - (5.0f + 5.0f * (float)kk);
      gin[2 + kk] = expf(-(1.f / 25.f) * u * u);
    }
    float accv = 0.f;
    for (int h = 0; h < 32; ++h) {
      float z = b1l[h];
#pragma unroll
      for (int kk = 0; kk < 10; ++kk) z += gin[kk] * w1l[kk * 32 + h];
      accv += silu_f(z) * w2l[h];
    }
    accv += b2v;
    vals[e] = base * (1.f + tanhf(accv));
  }
  lut[i] = make_float2(vals[0], vals[1] - vals[0]);
}

// ---------------------------------------------------------------- per-atom src MLP
// 32 atoms/block (2 waves x 16). Register-tiled: lane=(h4,a4) holds 4h x 4a.
__global__ __launch_bounds__(128) void k_src(
    const float* __restrict__ x,
    const float* __restrict__ g, const float* __restrict__ bb,
    const float* __restrict__ w1, const float* __restrict__ b1,
    const float* __restrict__ w2, const float* __restrict__ b2,
    const float* __restrict__ lng, const float* __restrict__ lnb,
    float* __restrict__ srcout) {
  int t = threadIdx.x, wave = t >> 6, lane = t & 63;
  __shared__ __align__(16) float w1s[FD * HD];      // 32 KB [k][h]
  __shared__ __align__(16) float w2s[HD * DD];      // 4 KB  [h][c]
  __shared__ __align__(16) float xnsA[2][FD][16];   // 16 KB [k][a]
  __shared__ __align__(16) float hbA[2][HD][16];    // 8 KB  [h][a]

  for (int idx = t; idx < FD * HD / 4; idx += 128)
    ((float4*)w1s)[idx] = ((const float4*)w1)[idx];
  for (int idx = t; idx < HD * DD / 4; idx += 128)
    ((float4*)w2s)[idx] = ((const float4*)w2)[idx];

  int aBase = blockIdx.x * 32 + wave * 16;
  int al = lane & 15, part = lane >> 4;

  // LN(128): 4 lanes per atom, 32 dims each
  float xr[32];
  const float4* xp = (const float4*)(x + (size_t)(aBase + al) * FD + part * 32);
#pragma unroll
  for (int i = 0; i < 8; ++i) {
    float4 v = xp[i];
    xr[i*4] = v.x; xr[i*4+1] = v.y; xr[i*4+2] = v.z; xr[i*4+3] = v.w;
  }
  float s = 0.f;
#pragma unroll
  for (int i = 0; i < 32; ++i) s += xr[i];
  s += __shfl_xor(s, 16); s += __shfl_xor(s, 32);
  float m = s * (1.f / 128.f);
  float v2 = 0.f;
#pragma unroll
  for (int i = 0; i < 32; ++i) { float d = xr[i] - m; v2 += d * d; }
  v2 += __shfl_xor(v2, 16); v2 += __shfl_xor(v2, 32);
  float inv = rsqrtf(v2 * (1.f / 128.f) + 1e-5f);
#pragma unroll
  for (int i = 0; i < 32; ++i) {
    int k = part * 32 + i;
    xnsA[wave][k][al] = (xr[i] - m) * inv * g[k] + bb[k];
  }
  __syncthreads();

  // hidden 128->64
  int h0 = al * 4, a0 = part * 4;
  float acc[4][4] = {};
#pragma unroll 4
  for (int k = 0; k < FD; ++k) {
    float4 wv = *(const float4*)&w1s[k * HD + h0];
    float4 xa = *(const float4*)&xnsA[wave][k][a0];
    acc[0][0] += wv.x * xa.x; acc[0][1] += wv.x * xa.y; acc[0][2] += wv.x * xa.z; acc[0][3] += wv.x * xa.w;
    acc[1][0] += wv.y * xa.x; acc[1][1] += wv.y * xa.y; acc[1][2] += wv.y * xa.z; acc[1][3] += wv.y * xa.w;
    acc[2][0] += wv.z * xa.x; acc[2][1] += wv.z * xa.y; acc[2][2] += wv.z * xa.z; acc[2][3] += wv.z * xa.w;
    acc[3][0] += wv.w * xa.x; acc[3][1] += wv.w * xa.y; acc[3][2] += wv.w * xa.z; acc[3][3] += wv.w * xa.w;
  }
#pragma unroll
  for (int i = 0; i < 4; ++i) {
    float bh = b1[h0 + i];
    float4 o;
    o.x = silu_f(acc[i][0] + bh); o.y = silu_f(acc[i][1] + bh);
    o.z = silu_f(acc[i][2] + bh); o.w = silu_f(acc[i][3] + bh);
    *(float4*)&hbA[wave][h0 + i][a0] = o;
  }
  __syncthreads();

  // 64->16 + LN(16)
  float acc2[4] = {};
#pragma unroll 4
  for (int h = 0; h < HD; ++h) {
    float wv = w2s[h * DD + al];
    float4 hv = *(const float4*)&hbA[wave][h][a0];
    acc2[0] += wv * hv.x; acc2[1] += wv * hv.y; acc2[2] += wv * hv.z; acc2[3] += wv * hv.w;
  }
  float b2c = b2[al], lgc = lng[al], lbc = lnb[al];
#pragma unroll
  for (int j = 0; j < 4; ++j) {
    float val = acc2[j] + b2c;
    float sm = val;
    sm += __shfl_xor(sm, 1); sm += __shfl_xor(sm, 2); sm += __shfl_xor(sm, 4); sm += __shfl_xor(sm, 8);
    float mm = sm * (1.f / 16.f);
    float dv = val - mm;
    float vv = dv * dv;
    vv += __shfl_xor(vv, 1); vv += __shfl_xor(vv, 2); vv += __shfl_xor(vv, 4); vv += __shfl_xor(vv, 8);
    float iv = rsqrtf(vv * (1.f / 16.f) + 1e-5f);
    srcout[(size_t)(aBase + a0 + j) * DD + al] = dv * iv * lgc + lbc;
  }
}

// ------------------------------------------------- graph-mean neutralization (coalesced)
__global__ __launch_bounds__(256) void k_center(float* __restrict__ src) {
  int gph = blockIdx.x, t = threadIdx.x;
  float4* s4 = (float4*)(src + (size_t)gph * N_A * DD);   // 2048 float4
  float4 acc = make_float4(0.f, 0.f, 0.f, 0.f);
#pragma unroll
  for (int i = 0; i < 8; ++i) {
    float4 v = s4[t + 256 * i];
    acc.x += v.x; acc.y += v.y; acc.z += v.z; acc.w += v.w;
  }
  __shared__ float4 red[256];
  red[t] = acc;
  __syncthreads();
  if (t < 64) {
    float4 a = red[t], b = red[t + 64], c = red[t + 128], d = red[t + 192];
    a.x += b.x + c.x + d.x; a.y += b.y + c.y + d.y;
    a.z += b.z + c.z + d.z; a.w += b.w + c.w + d.w;
    red[t] = a;
  }
  __syncthreads();
  if (t < 16) {
    float4 a = red[t], b = red[t + 16], c = red[t + 32], d = red[t + 48];
    a.x += b.x + c.x + d.x; a.y += b.y + c.y + d.y;
    a.z += b.z + c.z + d.z; a.w += b.w + c.w + d.w;
    red[t] = a;
  }
  __syncthreads();
  if (t < 4) {
    float4 a = red[t], b = red[t + 4], c = red[t + 8], d = red[t + 12];
    a.x = (a.x + b.x + c.x + d.x) * (1.f / 512.f);
    a.y = (a.y + b.y + c.y + d.y) * (1.f / 512.f);
    a.z = (a.z + b.z + c.z + d.z) * (1.f / 512.f);
    a.w = (a.w + b.w + c.w + d.w) * (1.f / 512.f);
    red[t] = a;
  }
  __syncthreads();
  float4 mv = red[t & 3];
#pragma unroll
  for (int i = 0; i < 8; ++i) {
    int idx = t + 256 * i;
    float4 v = s4[idx];
    v.x -= mv.x; v.y -= mv.y; v.z -= mv.z; v.w -= mv.w;
    s4[idx] = v;
  }
}

// ---------------------------------------------------------------- pair stage
__global__ __launch_bounds__(256) void k_pairs(
    const float* __restrict__ pos, const float* __restrict__ src,
    const float2* __restrict__ lut, float* __restrict__ shell) {
  int gph = blockIdx.x >> 7;
  int blk = blockIdx.x & 127;
  int t = threadIdx.x, wave = t >> 6, lane = t & 63;
  int i_local = blk * 4 + wave;

  __shared__ __align__(16) float sp[N_A * 3];        // 6 KB
  __shared__ __align__(16) float ss[N_A * DD];       // 32 KB
  __shared__ __align__(16) float2 luts[NLUT];        // 8 KB
  __shared__ __align__(16) float wb[4][N_A];         // 8 KB
  __shared__ unsigned char tbs[4][N_A];              // 2 KB

  for (int idx = t; idx < N_A * 3 / 4; idx += 256)
    ((float4*)sp)[idx] = ((const float4*)(pos + (size_t)gph * N_A * 3))[idx];
  for (int idx = t; idx < N_A * DD / 4; idx += 256)
    ((float4*)ss)[idx] = ((const float4*)(src + (size_t)gph * N_A * DD))[idx];
  for (int idx = t; idx < NLUT / 2; idx += 256)
    ((float4*)luts)[idx] = ((const float4*)lut)[idx];
  __syncthreads();

  float px = sp[i_local * 3], py = sp[i_local * 3 + 1], pz = sp[i_local * 3 + 2];
  float cnt[5] = {0,0,0,0,0}, sd[5] = {0,0,0,0,0}, sdd[5] = {0,0,0,0,0};
  const float lscale = (float)(NLUT - 1) / DMAXF;

#pragma unroll
  for (int it = 0; it < 8; ++it) {
    int jv = lane + it * 64;
    float dx = px - sp[jv * 3], dy = py - sp[jv * 3 + 1], dz = pz - sp[jv * 3 + 2];
    float d2 = dx * dx + dy * dy + dz * dz + 1e-12f;
    float d = sqrtf(d2);
    bool valid = (jv != i_local) && (d >= 5.0f);
    int tq = (d >= 10.f) + (d >= 20.f) + (d >= 40.f) + (d >= 80.f);
    float xq = d * lscale;
    int i0 = min((int)xq, NLUT - 2);
    float f = xq - (float)i0;
    float2 L = luts[i0];
    float w = valid ? (L.x + L.y * f) : 0.f;
    wb[wave][jv] = w;
    tbs[wave][jv] = (unsigned char)tq;
    float dm = valid ? d : 0.f;
    float ddm = valid ? d * d : 0.f;
    float cm = valid ? 1.f : 0.f;
#pragma unroll
    for (int q = 0; q < 5; ++q) {
      bool mq = (tq == q);
      cnt[q] += mq ? cm : 0.f;
      sd[q]  += mq ? dm : 0.f;
      sdd[q] += mq ? ddm : 0.f;
    }
  }
#pragma unroll
  for (int q = 0; q < 5; ++q) {
#pragma unroll
    for (int o = 32; o > 0; o >>= 1) {
      cnt[q] += __shfl_xor(cnt[q], o);
      sd[q]  += __shfl_xor(sd[q], o);
      sdd[q] += __shfl_xor(sdd[q], o);
    }
  }
  __syncthreads();

  // phase 2: lane = (j = lane&15, c-quad = lane>>4); b128 ss reads, imm offsets
  int jlow = lane & 15, cq = lane >> 4;
  float accq[5][4] = {};
  const float* ssb = &ss[jlow * DD + cq * 4];
  const float* wbb = &wb[wave][jlow];
  const unsigned char* tbb = &tbs[wave][jlow];
#pragma unroll
  for (int jj = 0; jj < 32; ++jj) {
    float4 sv = *(const float4*)(ssb + jj * 256);   // j = jj*16 + jlow
    float w = wbb[jj * 16];
    int tq = tbb[jj * 16];
    float w0 = (tq == 0) ? w : 0.f;
    float w1_ = (tq == 1) ? w : 0.f;
    float w2_ = (tq == 2) ? w : 0.f;
    float w3_ = (tq == 3) ? w : 0.f;
    float w4_ = (tq == 4) ? w : 0.f;
    accq[0][0] += w0 * sv.x; accq[0][1] += w0 * sv.y; accq[0][2] += w0 * sv.z; accq[0][3] += w0 * sv.w;
    accq[1][0] += w1_ * sv.x; accq[1][1] += w1_ * sv.y; accq[1][2] += w1_ * sv.z; accq[1][3] += w1_ * sv.w;
    accq[2][0] += w2_ * sv.x; accq[2][1] += w2_ * sv.y; accq[2][2] += w2_ * sv.z; accq[2][3] += w2_ * sv.w;
    accq[3][0] += w3_ * sv.x; accq[3][1] += w3_ * sv.y; accq[3][2] += w3_ * sv.z; accq[3][3] += w3_ * sv.w;
    accq[4][0] += w4_ * sv.x; accq[4][1] += w4_ * sv.y; accq[4][2] += w4_ * sv.z; accq[4][3] += w4_ * sv.w;
  }
#pragma unroll
  for (int q = 0; q < 5; ++q)
#pragma unroll
    for (int i = 0; i < 4; ++i) {
      float v = accq[q][i];
      v += __shfl_xor(v, 1); v += __shfl_xor(v, 2); v += __shfl_xor(v, 4); v += __shfl_xor(v, 8);
      accq[q][i] = v;
    }

  float* shp = shell + (size_t)(gph * N_A + i_local) * SEIN;
  if (jlow == 0) {
#pragma unroll
    for (int q = 0; q < 5; ++q)
#pragma unroll
      for (int i = 0; i < 4; ++i)
        shp[q * 19 + cq * 4 + i] = accq[q][i] / fmaxf(cnt[q], 1.f);
  }
  if (lane < 5) {
    int q = lane;
    float denom = fmaxf(cnt[q], 1.f);
    shp[q * 19 + 16] = cnt[q];
    shp[q * 19 + 17] = sd[q] / denom;
    shp[q * 19 + 18] = sqrtf(sdd[q] / denom + 1e-12f);
  }
}

// ---------------------------------------------------------------- tail A: emb
// 32 atoms/block (2 waves x 16); register-tiled
__global__ __launch_bounds__(128) void k_tail_a(
    const float* __restrict__ shell,
    const float* __restrict__ se_ln_g, const float* __restrict__ se_ln_b,
    const float* __restrict__ se_w1, const float* __restrict__ se_b1,
    const float* __restrict__ se_w2, const float* __restrict__ se_b2,
    float* __restrict__ emb) {
  int t = threadIdx.x, wave = t >> 6, lane = t & 63;
  __shared__ __align__(16) float w1s[SEIN * HD];      // 24.3 KB [k][h]
  __shared__ __align__(16) float w2s[HD * DD];        // 4 KB
  __shared__ __align__(16) float shnA[2][SEIN][16];   // 12.2 KB [k][a]
  __shared__ __align__(16) float hbA[2][HD][16];      // 8 KB

  for (int idx = t; idx < SEIN * HD / 4; idx += 128)
    ((float4*)w1s)[idx] = ((const float4*)se_w1)[idx];
  for (int idx = t; idx < HD * DD / 4; idx += 128)
    ((float4*)w2s)[idx] = ((const float4*)se_w2)[idx];

  int aB = blockIdx.x * 32;
  // coalesced shell load -> k-major LDS (magic div by 95)
  const float* shg = shell + (size_t)aB * SEIN;
  for (int idx = t; idx < 32 * SEIN; idx += 128) {
    unsigned a_loc = ((unsigned)idx * 690u) >> 16;   // idx/95 for idx<3040
    int kk = idx - (int)a_loc * SEIN;
    shnA[a_loc >> 4][kk][a_loc & 15] = shg[idx];
  }
  __syncthreads();

  int al = lane & 15, part = lane >> 4;
  // LN(95) atom-parallel, single pass stats
  float s1 = 0.f, sq = 0.f;
  for (int i = 0; i < 24; ++i) {
    int k = part * 24 + i;
    if (k < SEIN) { float v = shnA[wave][k][al]; s1 += v; sq += v * v; }
  }
  s1 += __shfl_xor(s1, 16); s1 += __shfl_xor(s1, 32);
  sq += __shfl_xor(sq, 16); sq += __shfl_xor(sq, 32);
  float m = s1 * (1.f / (float)SEIN);
  float var = sq * (1.f / (float)SEIN) - m * m;
  float inv = rsqrtf(var + 1e-5f);
  for (int i = 0; i < 24; ++i) {
    int k = part * 24 + i;
    if (k < SEIN)
      shnA[wave][k][al] = (shnA[wave][k][al] - m) * inv * se_ln_g[k] + se_ln_b[k];
  }
  __syncthreads();

  int h0 = al * 4, a0 = part * 4;
  float acc[4][4] = {};
#pragma unroll 5
  for (int k = 0; k < SEIN; ++k) {
    float4 wv = *(const float4*)&w1s[k * HD + h0];
    float4 xa = *(const float4*)&shnA[wave][k][a0];
    acc[0][0] += wv.x * xa.x; acc[0][1] += wv.x * xa.y; acc[0][2] += wv.x * xa.z; acc[0][3] += wv.x * xa.w;
    acc[1][0] += wv.y * xa.x; acc[1][1] += wv.y * xa.y; acc[1][2] += wv.y * xa.z; acc[1][3] += wv.y * xa.w;
    acc[2][0] += wv.z * xa.x; acc[2][1] += wv.z * xa.y; acc[2][2] += wv.z * xa.z; acc[2][3] += wv.z * xa.w;
    acc[3][0] += wv.w * xa.x; acc[3][1] += wv.w * xa.y; acc[3][2] += wv.w * xa.z; acc[3][3] += wv.w * xa.w;
  }
#pragma unroll
  for (int i = 0; i < 4; ++i) {
    float bh = se_b1[h0 + i];
    float4 o;
    o.x = silu_f(acc[i][0] + bh); o.y = silu_f(acc[i][1] + bh);
    o.z = silu_f(acc[i][2] + bh); o.w = silu_f(acc[i][3] + bh);
    *(float4*)&hbA[wave][h0 + i][a0] = o;
  }
  __syncthreads();

  float acc2[4] = {};
#pragma unroll 4
  for (int h = 0; h < HD; ++h) {
    float wv = w2s[h * DD + al];
    float4 hv = *(const float4*)&hbA[wave][h][a0];
    acc2[0] += wv * hv.x; acc2[1] += wv * hv.y; acc2[2] += wv * hv.z; acc2[3] += wv * hv.w;
  }
  float b2c = se_b2[al];
#pragma unroll
  for (int j = 0; j < 4; ++j)
    emb[(size_t)(aB + wave * 16 + a0 + j) * DD + al] = acc2[j] + b2c;
}

// ---------------------------------------------------------------- tail B: energy
__global__ __launch_bounds__(128) void k_tail_b(
    const float* __restrict__ src, const float* __restrict__ embp,
    const float* __restrict__ shell,
    const float* __restrict__ eh_ln_g, const float* __restrict__ eh_ln_b,
    const float* __restrict__ eh_w1, const float* __restrict__ eh_b1,
    const float* __restrict__ eh_w2, const float* __restrict__ eh_b2,
    const float* __restrict__ far_gate, const float* __restrict__ energy_scale,
    float* __restrict__ out) {
  int t = threadIdx.x, wave = t >> 6, lane = t & 63;
  __shared__ __align__(16) float w1s[EHIN * HD];      // 40.7 KB [k][h]
  __shared__ __align__(16) float einA[2][EHIN][16];   // 20.4 KB [k][a]
  __shared__ float redv[2][4];

  for (int idx = t; idx < EHIN * HD / 4; idx += 128)
    ((float4*)w1s)[idx] = ((const float4*)eh_w1)[idx];

  int aB = blockIdx.x * 32;
  int gph = aB >> 9;

  // build ein: [src, emb, src*emb, src-emb] rows 0..63
  for (int idx = t; idx < 32 * DD; idx += 128) {
    int a_loc = idx >> 4, k = idx & 15;
    float sv = src[(size_t)aB * DD + idx];
    float ev = embp[(size_t)aB * DD + idx];
    int wv_ = a_loc >> 4, ac = a_loc & 15;
    einA[wv_][k][ac] = sv;
    einA[wv_][16 + k][ac] = ev;
    einA[wv_][32 + k][ac] = sv * ev;
    einA[wv_][48 + k][ac] = sv - ev;
  }
  // shell rows 64..158 (coalesced, magic div by 95)
  const float* shg = shell + (size_t)aB * SEIN;
  for (int idx = t; idx < 32 * SEIN; idx += 128) {
    unsigned a_loc = ((unsigned)idx * 690u) >> 16;
    int kk = idx - (int)a_loc * SEIN;
    einA[a_loc >> 4][64 + kk][a_loc & 15] = shg[idx];
  }
  __syncthreads();

  int al = lane & 15, part = lane >> 4;
  // LN(159) atom-parallel
  float s1 = 0.f, sq = 0.f;
  for (int i = 0; i < 40; ++i) {
    int k = part * 40 + i;
    if (k < EHIN) { float v = einA[wave][k][al]; s1 += v; sq += v * v; }
  }
  s1 += __shfl_xor(s1, 16); s1 += __shfl_xor(s1, 32);
  sq += __shfl_xor(sq, 16); sq += __shfl_xor(sq, 32);
  float m = s1 * (1.f / (float)EHIN);
  float var = sq * (1.f / (float)EHIN) - m * m;
  float inv = rsqrtf(var + 1e-5f);
  for (int i = 0; i < 40; ++i) {
    int k = part * 40 + i;
    if (k < EHIN)
      einA[wave][k][al] = (einA[wave][k][al] - m) * inv * eh_ln_g[k] + eh_ln_b[k];
  }
  __syncthreads();

  int h0 = al * 4, a0 = part * 4;
  float acc[4][4] = {};
#pragma unroll 3
  for (int k = 0; k < EHIN; ++k) {
    float4 wv = *(const float4*)&w1s[k * HD + h0];
    float4 xa = *(const float4*)&einA[wave][k][a0];
    acc[0][0] += wv.x * xa.x; acc[0][1] += wv.x * xa.y; acc[0][2] += wv.x * xa.z; acc[0][3] += wv.x * xa.w;
    acc[1][0] += wv.y * xa.x; acc[1][1] += wv.y * xa.y; acc[1][2] += wv.y * xa.z; acc[1][3] += wv.y * xa.w;
    acc[2][0] += wv.z * xa.x; acc[2][1] += wv.z * xa.y; acc[2][2] += wv.z * xa.z; acc[2][3] += wv.z * xa.w;
    acc[3][0] += wv.w * xa.x; acc[3][1] += wv.w * xa.y; acc[3][2] += wv.w * xa.z; acc[3][3] += wv.w * xa.w;
  }
  float pa[4] = {0.f, 0.f, 0.f, 0.f};
#pragma unroll
  for (int i = 0; i < 4; ++i) {
    float bh = eh_b1[h0 + i];
    float w2v = eh_w2[h0 + i];
#pragma unroll
    for (int j = 0; j < 4; ++j) pa[j] += silu_f(acc[i][j] + bh) * w2v;
  }
#pragma unroll
  for (int j = 0; j < 4; ++j) {
    pa[j] += __shfl_xor(pa[j], 1); pa[j] += __shfl_xor(pa[j], 2);
    pa[j] += __shfl_xor(pa[j], 4); pa[j] += __shfl_xor(pa[j], 8);
  }
  if (al == 0) redv[wave][part] = pa[0] + pa[1] + pa[2] + pa[3] + 4.f * eh_b2[0];
  __syncthreads();
  if (t == 0) {
    float tot = 0.f;
#pragma unroll
    for (int w2_ = 0; w2_ < 2; ++w2_)
#pragma unroll
      for (int p = 0; p < 4; ++p) tot += redv[w2_][p];
    atomicAdd(&out[gph], tot * tanhf(far_gate[0]) * expf(energy_scale[0]));
  }
}

// ---------------------------------------------------------------- launch
extern "C" void kernel_launch(void* const* d_in, const int* in_sizes, int n_in,
                              void* d_out, int out_size, void* d_ws, size_t ws_size,
                              hipStream_t stream) {
  const float* x         = (const float*)d_in[0];
  const float* pos       = (const float*)d_in[1];
  const float* in_ln_g   = (const float*)d_in[4];
  const float* in_ln_b   = (const float*)d_in[5];
  const float* src_w1    = (const float*)d_in[6];
  const float* src_b1    = (const float*)d_in[7];
  const float* src_w2    = (const float*)d_in[8];
  const float* src_b2    = (const float*)d_in[9];
  const float* src_ln_g  = (const float*)d_in[10];
  const float* src_ln_b  = (const float*)d_in[11];
  const float* se_ln_g   = (const float*)d_in[12];
  const float* se_ln_b   = (const float*)d_in[13];
  const float* se_w1     = (const float*)d_in[14];
  const float* se_b1     = (const float*)d_in[15];
  const float* se_w2     = (const float*)d_in[16];
  const float* se_b2     = (const float*)d_in[17];
  const float* eh_ln_g   = (const float*)d_in[18];
  const float* eh_ln_b   = (const float*)d_in[19];
  const float* eh_w1     = (const float*)d_in[20];
  const float* eh_b1     = (const float*)d_in[21];
  const float* eh_w2     = (const float*)d_in[22];
  const float* eh_b2     = (const float*)d_in[23];
  const float* k_screen  = (const float*)d_in[24];
  const float* kg_w1     = (const float*)d_in[25];
  const float* kg_b1     = (const float*)d_in[26];
  const float* kg_w2     = (const float*)d_in[27];
  const float* kg_b2     = (const float*)d_in[28];
  const float* far_gate  = (const float*)d_in[29];
  const float* en_scale  = (const float*)d_in[30];
  float* out = (float*)d_out;

  float* ws_src   = (float*)d_ws;                            // M*16
  float* ws_shell = ws_src + (size_t)M_AT * DD;              // M*95
  float* ws_emb   = ws_shell + (size_t)M_AT * SEIN;          // M*16
  float2* ws_lut  = (float2*)(ws_emb + (size_t)M_AT * DD);   // NLUT float2

  k_lut2<<<NLUT / 256, 256, 0, stream>>>(k_screen, kg_w1, kg_b1, kg_w2, kg_b2,
                                         ws_lut, out);
  k_src<<<M_AT / 32, 128, 0, stream>>>(x, in_ln_g, in_ln_b, src_w1, src_b1,
                                       src_w2, src_b2, src_ln_g, src_ln_b, ws_src);
  k_center<<<B_G, 256, 0, stream>>>(ws_src);
  k_pairs<<<B_G * (N_A / 4), 256, 0, stream>>>(pos, ws_src, ws_lut, ws_shell);
  k_tail_a<<<M_AT / 32, 128, 0, stream>>>(ws_shell, se_ln_g, se_ln_b,
                                          se_w1, se_b1, se_w2, se_b2, ws_emb);
  k_tail_b<<<M_AT / 32, 128, 0, stream>>>(ws_src, ws_emb, ws_shell,
                                          eh_ln_g, eh_ln_b, eh_w1, eh_b1, eh_w2, eh_b2,
                                          far_gate, en_scale, out);
}

// Round 4
// 209.300 us; speedup vs baseline: 1.5635x; 1.0557x over previous
//
#include <hip/hip_runtime.h>
#include <hip/hip_bf16.h>
#include <math.h>

#define B_G   16
#define N_A   512
#define M_AT  8192
#define FD    128
#define HD    64
#define DD    16
#define SEIN  95
#define EHIN  159
#define NLUT  512
#define DMAXF 140.0f

__device__ __forceinline__ float silu_f(float z) { return z / (1.f + __expf(-z)); }

// ================================================================ k_front
// blocks 0..255: src MLP, 32 atoms each (2 waves x 16 atoms), weights from global.
// blocks 256..259: kernel-LUT (512 entries) + zero out[16].
__global__ __launch_bounds__(128) void k_front(
    const float* __restrict__ x,
    const float* __restrict__ g, const float* __restrict__ bb,
    const float* __restrict__ w1, const float* __restrict__ b1,
    const float* __restrict__ w2, const float* __restrict__ b2,
    const float* __restrict__ lng, const float* __restrict__ lnb,
    const float* __restrict__ k_screen,
    const float* __restrict__ kg_w1, const float* __restrict__ kg_b1,
    const float* __restrict__ kg_w2, const float* __restrict__ kg_b2,
    float* __restrict__ srcout, float* __restrict__ partials,
    float2* __restrict__ lut, float* __restrict__ out) {
  int t = threadIdx.x;

  if (blockIdx.x >= 256) {
    // ---------------- LUT block ----------------
    int lb = blockIdx.x - 256;
    __shared__ float w1l[320], b1l[32], w2l[32];
    if (lb == 0 && t < B_G) out[t] = 0.f;
    for (int idx = t; idx < 320; idx += 128) w1l[idx] = kg_w1[idx];
    if (t < 32) { b1l[t] = kg_b1[t]; w2l[t] = kg_w2[t]; }
    __syncthreads();
    int i = lb * 128 + t;
    float step = DMAXF / (float)(NLUT - 1);
    float ksv = k_screen[0];
    float screening = fmaxf(ksv, 0.f) + log1pf(expf(-fabsf(ksv)));
    float b2v = kg_b2[0];
    float vals[2];
#pragma unroll
    for (int e = 0; e < 2; ++e) {
      int ii = min(i + e, NLUT - 1);
      float d = (float)ii * step;
      float base = expf(-screening * d) / fmaxf(d, 1e-6f);
      float gin[10];
      gin[0] = d * (1.f / 5.0f);
      gin[1] = d * (1.f / 40.0f);
#pragma unroll
      for (int kk = 0; kk < 8; ++kk) {
        float u = d - (5.0f + 5.0f * (float)kk);
        gin[2 + kk] = expf(-(1.f / 25.f) * u * u);
      }
      float accv = 0.f;
      for (int h = 0; h < 32; ++h) {
        float z = b1l[h];
#pragma unroll
        for (int kk = 0; kk < 10; ++kk) z += gin[kk] * w1l[kk * 32 + h];
        accv += silu_f(z) * w2l[h];
      }
      vals[e] = base * (1.f + tanhf(accv + b2v));
    }
    lut[i] = make_float2(vals[0], vals[1] - vals[0]);
    return;
  }

  // ---------------- src block ----------------
  int wave = t >> 6, lane = t & 63;
  __shared__ __align__(16) float xnsA[2][FD][16];   // 16 KB [k][a]
  __shared__ __align__(16) float hbA[2][HD][16];    // 8 KB  [h][a]
  __shared__ float psum[2][16];

  int aBase = blockIdx.x * 32 + wave * 16;
  int al = lane & 15, prt = lane >> 4;

  // LN(128): 4 lanes per atom, 32 dims each
  float xr[32];
  const float4* xp = (const float4*)(x + (size_t)(aBase + al) * FD + prt * 32);
#pragma unroll
  for (int i = 0; i < 8; ++i) {
    float4 v = xp[i];
    xr[i*4] = v.x; xr[i*4+1] = v.y; xr[i*4+2] = v.z; xr[i*4+3] = v.w;
  }
  float s = 0.f;
#pragma unroll
  for (int i = 0; i < 32; ++i) s += xr[i];
  s += __shfl_xor(s, 16); s += __shfl_xor(s, 32);
  float m = s * (1.f / 128.f);
  float v2 = 0.f;
#pragma unroll
  for (int i = 0; i < 32; ++i) { float d = xr[i] - m; v2 += d * d; }
  v2 += __shfl_xor(v2, 16); v2 += __shfl_xor(v2, 32);
  float inv = rsqrtf(v2 * (1.f / 128.f) + 1e-5f);
#pragma unroll
  for (int i = 0; i < 32; ++i) {
    int k = prt * 32 + i;
    xnsA[wave][k][al] = (xr[i] - m) * inv * g[k] + bb[k];
  }
  __syncthreads();

  // hidden 128->64 (weights streamed from global)
  int h0 = al * 4, a0 = prt * 4;
  float acc[4][4] = {};
#pragma unroll 4
  for (int k = 0; k < FD; ++k) {
    float4 wv = ((const float4*)(w1 + (size_t)k * HD))[al];
    float4 xa = *(const float4*)&xnsA[wave][k][a0];
    acc[0][0] += wv.x * xa.x; acc[0][1] += wv.x * xa.y; acc[0][2] += wv.x * xa.z; acc[0][3] += wv.x * xa.w;
    acc[1][0] += wv.y * xa.x; acc[1][1] += wv.y * xa.y; acc[1][2] += wv.y * xa.z; acc[1][3] += wv.y * xa.w;
    acc[2][0] += wv.z * xa.x; acc[2][1] += wv.z * xa.y; acc[2][2] += wv.z * xa.z; acc[2][3] += wv.z * xa.w;
    acc[3][0] += wv.w * xa.x; acc[3][1] += wv.w * xa.y; acc[3][2] += wv.w * xa.z; acc[3][3] += wv.w * xa.w;
  }
  {
    float4 bv = ((const float4*)b1)[al];
    float bh[4] = {bv.x, bv.y, bv.z, bv.w};
#pragma unroll
    for (int i = 0; i < 4; ++i) {
      float4 o;
      o.x = silu_f(acc[i][0] + bh[i]); o.y = silu_f(acc[i][1] + bh[i]);
      o.z = silu_f(acc[i][2] + bh[i]); o.w = silu_f(acc[i][3] + bh[i]);
      *(float4*)&hbA[wave][h0 + i][a0] = o;
    }
  }
  __syncthreads();

  // 64->16 + LN(16)
  float acc2[4] = {};
#pragma unroll 4
  for (int h = 0; h < HD; ++h) {
    float wv = w2[h * DD + al];
    float4 hv = *(const float4*)&hbA[wave][h][a0];
    acc2[0] += wv * hv.x; acc2[1] += wv * hv.y; acc2[2] += wv * hv.z; acc2[3] += wv * hv.w;
  }
  float b2c = b2[al], lgc = lng[al], lbc = lnb[al];
  float lsum = 0.f;
#pragma unroll
  for (int j = 0; j < 4; ++j) {
    float val = acc2[j] + b2c;
    float sm = val;
    sm += __shfl_xor(sm, 1); sm += __shfl_xor(sm, 2); sm += __shfl_xor(sm, 4); sm += __shfl_xor(sm, 8);
    float mm = sm * (1.f / 16.f);
    float dv = val - mm;
    float vv = dv * dv;
    vv += __shfl_xor(vv, 1); vv += __shfl_xor(vv, 2); vv += __shfl_xor(vv, 4); vv += __shfl_xor(vv, 8);
    float iv = rsqrtf(vv * (1.f / 16.f) + 1e-5f);
    float ov = dv * iv * lgc + lbc;
    srcout[(size_t)(aBase + a0 + j) * DD + al] = ov;
    lsum += ov;
  }
  // per-block partial sum of src (for graph-mean neutralization downstream)
  lsum += __shfl_xor(lsum, 16); lsum += __shfl_xor(lsum, 32);
  if (lane < 16) psum[wave][al] = lsum;
  __syncthreads();
  if (t < 16) partials[(size_t)blockIdx.x * 16 + t] = psum[0][t] + psum[1][t];
}

// ================================================================ k_pairs
// one wave per atom i; 4 atoms per 256-thread block; graph + LUT staged in LDS.
// Mean-centering applied algebraically via per-shell sum-of-weights (sw).
__global__ __launch_bounds__(256) void k_pairs(
    const float* __restrict__ pos, const float* __restrict__ src,
    const float2* __restrict__ lut, const float* __restrict__ partials,
    float* __restrict__ shell) {
  int gph = blockIdx.x >> 7;
  int blk = blockIdx.x & 127;
  int t = threadIdx.x, wave = t >> 6, lane = t & 63;
  int i_local = blk * 4 + wave;

  __shared__ __align__(16) float sp[N_A * 3];        // 6 KB
  __shared__ __align__(16) float ss[N_A * DD];       // 32 KB
  __shared__ __align__(16) float2 luts[NLUT];        // 4 KB
  __shared__ __align__(16) float wb[4][N_A];         // 8 KB
  __shared__ unsigned char tbs[4][N_A];              // 2 KB
  __shared__ float smean[16];

  for (int idx = t; idx < N_A * 3 / 4; idx += 256)
    ((float4*)sp)[idx] = ((const float4*)(pos + (size_t)gph * N_A * 3))[idx];
  for (int idx = t; idx < N_A * DD / 4; idx += 256)
    ((float4*)ss)[idx] = ((const float4*)(src + (size_t)gph * N_A * DD))[idx];
  if (t < NLUT / 2) ((float4*)luts)[t] = ((const float4*)lut)[t];
  if (t < 64) {  // wave 0: graph mean from partials
    int c = t & 15, grp = t >> 4;
    float sm = 0.f;
#pragma unroll
    for (int k = 0; k < 4; ++k)
      sm += partials[(size_t)(gph * 16 + grp * 4 + k) * 16 + c];
    sm += __shfl_xor(sm, 16); sm += __shfl_xor(sm, 32);
    if (t < 16) smean[c] = sm * (1.f / 512.f);
  }
  __syncthreads();

  float px = sp[i_local * 3], py = sp[i_local * 3 + 1], pz = sp[i_local * 3 + 2];
  float cnt[5] = {0,0,0,0,0}, sd[5] = {0,0,0,0,0}, sdd[5] = {0,0,0,0,0}, sw[5] = {0,0,0,0,0};
  const float lscale = (float)(NLUT - 1) / DMAXF;

#pragma unroll
  for (int it = 0; it < 8; ++it) {
    int jv = lane + it * 64;
    float dx = px - sp[jv * 3], dy = py - sp[jv * 3 + 1], dz = pz - sp[jv * 3 + 2];
    float d2 = dx * dx + dy * dy + dz * dz + 1e-12f;
    float d = sqrtf(d2);
    bool valid = (jv != i_local) && (d >= 5.0f);
    int tq = (d >= 10.f) + (d >= 20.f) + (d >= 40.f) + (d >= 80.f);
    float xq = d * lscale;
    int i0 = min((int)xq, NLUT - 2);
    float f = xq - (float)i0;
    float2 L = luts[i0];
    float w = valid ? (L.x + L.y * f) : 0.f;
    wb[wave][jv] = w;
    tbs[wave][jv] = (unsigned char)tq;
    float dm = valid ? d : 0.f;
    float ddm = valid ? d * d : 0.f;
    float cm = valid ? 1.f : 0.f;
#pragma unroll
    for (int q = 0; q < 5; ++q) {
      bool mq = (tq == q);
      cnt[q] += mq ? cm : 0.f;
      sd[q]  += mq ? dm : 0.f;
      sdd[q] += mq ? ddm : 0.f;
      sw[q]  += mq ? w : 0.f;
    }
  }
#pragma unroll
  for (int q = 0; q < 5; ++q) {
#pragma unroll
    for (int o = 32; o > 0; o >>= 1) {
      cnt[q] += __shfl_xor(cnt[q], o);
      sd[q]  += __shfl_xor(sd[q], o);
      sdd[q] += __shfl_xor(sdd[q], o);
      sw[q]  += __shfl_xor(sw[q], o);
    }
  }
  __syncthreads();

  // phase 2: lane = (j = lane&15, c-quad = lane>>4); b128 ss reads, imm offsets
  int jlow = lane & 15, cq = lane >> 4;
  float accq[5][4] = {};
  const float* ssb = &ss[jlow * DD + cq * 4];
  const float* wbb = &wb[wave][jlow];
  const unsigned char* tbb = &tbs[wave][jlow];
#pragma unroll
  for (int jj = 0; jj < 32; ++jj) {
    float4 sv = *(const float4*)(ssb + jj * 256);   // j = jj*16 + jlow
    float w = wbb[jj * 16];
    int tq = tbb[jj * 16];
    float w0 = (tq == 0) ? w : 0.f;
    float w1_ = (tq == 1) ? w : 0.f;
    float w2_ = (tq == 2) ? w : 0.f;
    float w3_ = (tq == 3) ? w : 0.f;
    float w4_ = (tq == 4) ? w : 0.f;
    accq[0][0] += w0 * sv.x; accq[0][1] += w0 * sv.y; accq[0][2] += w0 * sv.z; accq[0][3] += w0 * sv.w;
    accq[1][0] += w1_ * sv.x; accq[1][1] += w1_ * sv.y; accq[1][2] += w1_ * sv.z; accq[1][3] += w1_ * sv.w;
    accq[2][0] += w2_ * sv.x; accq[2][1] += w2_ * sv.y; accq[2][2] += w2_ * sv.z; accq[2][3] += w2_ * sv.w;
    accq[3][0] += w3_ * sv.x; accq[3][1] += w3_ * sv.y; accq[3][2] += w3_ * sv.z; accq[3][3] += w3_ * sv.w;
    accq[4][0] += w4_ * sv.x; accq[4][1] += w4_ * sv.y; accq[4][2] += w4_ * sv.z; accq[4][3] += w4_ * sv.w;
  }
#pragma unroll
  for (int q = 0; q < 5; ++q)
#pragma unroll
    for (int i = 0; i < 4; ++i) {
      float v = accq[q][i];
      v += __shfl_xor(v, 1); v += __shfl_xor(v, 2); v += __shfl_xor(v, 4); v += __shfl_xor(v, 8);
      accq[q][i] = v;
    }

  float* shp = shell + (size_t)(gph * N_A + i_local) * SEIN;
  if (jlow == 0) {
#pragma unroll
    for (int q = 0; q < 5; ++q) {
      float denom = fmaxf(cnt[q], 1.f);
#pragma unroll
      for (int i = 0; i < 4; ++i) {
        int c = cq * 4 + i;
        shp[q * 19 + c] = (accq[q][i] - smean[c] * sw[q]) / denom;
      }
    }
  }
  if (lane < 5) {
    int q = lane;
    float denom = fmaxf(cnt[q], 1.f);
    shp[q * 19 + 16] = cnt[q];
    shp[q * 19 + 17] = sd[q] / denom;
    shp[q * 19 + 18] = sqrtf(sdd[q] / denom + 1e-12f);
  }
}

// ================================================================ k_tail
// fused se+eh MLPs; 32 atoms/block (2 waves x 16); weights streamed from global.
__global__ __launch_bounds__(128) void k_tail(
    const float* __restrict__ src, const float* __restrict__ shell,
    const float* __restrict__ partials,
    const float* __restrict__ se_ln_g, const float* __restrict__ se_ln_b,
    const float* __restrict__ se_w1, const float* __restrict__ se_b1,
    const float* __restrict__ se_w2, const float* __restrict__ se_b2,
    const float* __restrict__ eh_ln_g, const float* __restrict__ eh_ln_b,
    const float* __restrict__ eh_w1, const float* __restrict__ eh_b1,
    const float* __restrict__ eh_w2, const float* __restrict__ eh_b2,
    const float* __restrict__ far_gate, const float* __restrict__ energy_scale,
    float* __restrict__ out) {
  int t = threadIdx.x, wave = t >> 6, lane = t & 63;
  __shared__ __align__(16) float einA[2][EHIN][16];   // 20.4 KB [k][a]
  __shared__ __align__(16) float shnA[2][SEIN][16];   // 12.2 KB
  __shared__ __align__(16) float hbA[2][HD][16];      // 8 KB
  __shared__ float smean[16];
  __shared__ float redv[2][4];

  int aB = blockIdx.x * 32;
  int gph = aB >> 9;

  if (t < 64) {  // wave 0: graph mean
    int c = t & 15, grp = t >> 4;
    float sm = 0.f;
#pragma unroll
    for (int k = 0; k < 4; ++k)
      sm += partials[(size_t)(gph * 16 + grp * 4 + k) * 16 + c];
    sm += __shfl_xor(sm, 16); sm += __shfl_xor(sm, 32);
    if (t < 16) smean[c] = sm * (1.f / 512.f);
  }

  // stage raw shell -> einA rows 64..158, k-major (coalesced, magic div by 95)
  const float* shg = shell + (size_t)aB * SEIN;
  for (int idx = t; idx < 32 * SEIN; idx += 128) {
    unsigned a_loc = ((unsigned)idx * 690u) >> 16;
    int kk = idx - (int)a_loc * SEIN;
    einA[a_loc >> 4][64 + kk][a_loc & 15] = shg[idx];
  }
  __syncthreads();

  int al = lane & 15, prt = lane >> 4;
  // LN(95) -> shnA
  {
    float s1 = 0.f, sq = 0.f;
    for (int i = 0; i < 24; ++i) {
      int k = prt * 24 + i;
      if (k < SEIN) { float v = einA[wave][64 + k][al]; s1 += v; sq += v * v; }
    }
    s1 += __shfl_xor(s1, 16); s1 += __shfl_xor(s1, 32);
    sq += __shfl_xor(sq, 16); sq += __shfl_xor(sq, 32);
    float m = s1 * (1.f / (float)SEIN);
    float var = sq * (1.f / (float)SEIN) - m * m;
    float inv = rsqrtf(var + 1e-5f);
    for (int i = 0; i < 24; ++i) {
      int k = prt * 24 + i;
      if (k < SEIN)
        shnA[wave][k][al] = (einA[wave][64 + k][al] - m) * inv * se_ln_g[k] + se_ln_b[k];
    }
  }
  __syncthreads();

  int h0 = al * 4, a0 = prt * 4;
  // se hidden 95->64 (weights global)
  {
    float acc[4][4] = {};
#pragma unroll 5
    for (int k = 0; k < SEIN; ++k) {
      float4 wv = ((const float4*)(se_w1 + (size_t)k * HD))[al];
      float4 xa = *(const float4*)&shnA[wave][k][a0];
      acc[0][0] += wv.x * xa.x; acc[0][1] += wv.x * xa.y; acc[0][2] += wv.x * xa.z; acc[0][3] += wv.x * xa.w;
      acc[1][0] += wv.y * xa.x; acc[1][1] += wv.y * xa.y; acc[1][2] += wv.y * xa.z; acc[1][3] += wv.y * xa.w;
      acc[2][0] += wv.z * xa.x; acc[2][1] += wv.z * xa.y; acc[2][2] += wv.z * xa.z; acc[2][3] += wv.z * xa.w;
      acc[3][0] += wv.w * xa.x; acc[3][1] += wv.w * xa.y; acc[3][2] += wv.w * xa.z; acc[3][3] += wv.w * xa.w;
    }
    float4 bv = ((const float4*)se_b1)[al];
    float bh[4] = {bv.x, bv.y, bv.z, bv.w};
#pragma unroll
    for (int i = 0; i < 4; ++i) {
      float4 o;
      o.x = silu_f(acc[i][0] + bh[i]); o.y = silu_f(acc[i][1] + bh[i]);
      o.z = silu_f(acc[i][2] + bh[i]); o.w = silu_f(acc[i][3] + bh[i]);
      *(float4*)&hbA[wave][h0 + i][a0] = o;
    }
  }
  __syncthreads();

  // 64->16 -> emb (regs), build ein rows 0..63
  {
    float acc2[4] = {};
#pragma unroll 4
    for (int h = 0; h < HD; ++h) {
      float wv = se_w2[h * DD + al];
      float4 hv = *(const float4*)&hbA[wave][h][a0];
      acc2[0] += wv * hv.x; acc2[1] += wv * hv.y; acc2[2] += wv * hv.z; acc2[3] += wv * hv.w;
    }
    float b2c = se_b2[al], smc = smean[al];
    int aW = aB + wave * 16;
#pragma unroll
    for (int j = 0; j < 4; ++j) {
      float ev = acc2[j] + b2c;
      float sv = src[(size_t)(aW + a0 + j) * DD + al] - smc;
      einA[wave][al][a0 + j] = sv;
      einA[wave][16 + al][a0 + j] = ev;
      einA[wave][32 + al][a0 + j] = sv * ev;
      einA[wave][48 + al][a0 + j] = sv - ev;
    }
  }
  __syncthreads();

  // LN(159) in-place
  {
    float s1 = 0.f, sq = 0.f;
    for (int i = 0; i < 40; ++i) {
      int k = prt * 40 + i;
      if (k < EHIN) { float v = einA[wave][k][al]; s1 += v; sq += v * v; }
    }
    s1 += __shfl_xor(s1, 16); s1 += __shfl_xor(s1, 32);
    sq += __shfl_xor(sq, 16); sq += __shfl_xor(sq, 32);
    float m = s1 * (1.f / (float)EHIN);
    float var = sq * (1.f / (float)EHIN) - m * m;
    float inv = rsqrtf(var + 1e-5f);
    for (int i = 0; i < 40; ++i) {
      int k = prt * 40 + i;
      if (k < EHIN)
        einA[wave][k][al] = (einA[wave][k][al] - m) * inv * eh_ln_g[k] + eh_ln_b[k];
    }
  }
  __syncthreads();

  // eh hidden 159->64 (weights global), dot w2, reduce
  {
    float acc[4][4] = {};
#pragma unroll 3
    for (int k = 0; k < EHIN; ++k) {
      float4 wv = ((const float4*)(eh_w1 + (size_t)k * HD))[al];
      float4 xa = *(const float4*)&einA[wave][k][a0];
      acc[0][0] += wv.x * xa.x; acc[0][1] += wv.x * xa.y; acc[0][2] += wv.x * xa.z; acc[0][3] += wv.x * xa.w;
      acc[1][0] += wv.y * xa.x; acc[1][1] += wv.y * xa.y; acc[1][2] += wv.y * xa.z; acc[1][3] += wv.y * xa.w;
      acc[2][0] += wv.z * xa.x; acc[2][1] += wv.z * xa.y; acc[2][2] += wv.z * xa.z; acc[2][3] += wv.z * xa.w;
      acc[3][0] += wv.w * xa.x; acc[3][1] += wv.w * xa.y; acc[3][2] += wv.w * xa.z; acc[3][3] += wv.w * xa.w;
    }
    float4 b1v = ((const float4*)eh_b1)[al];
    float4 w2v = ((const float4*)eh_w2)[al];
    float bh[4] = {b1v.x, b1v.y, b1v.z, b1v.w};
    float wh[4] = {w2v.x, w2v.y, w2v.z, w2v.w};
    float pa[4] = {0.f, 0.f, 0.f, 0.f};
#pragma unroll
    for (int i = 0; i < 4; ++i)
#pragma unroll
      for (int j = 0; j < 4; ++j) pa[j] += silu_f(acc[i][j] + bh[i]) * wh[i];
#pragma unroll
    for (int j = 0; j < 4; ++j) {
      pa[j] += __shfl_xor(pa[j], 1); pa[j] += __shfl_xor(pa[j], 2);
      pa[j] += __shfl_xor(pa[j], 4); pa[j] += __shfl_xor(pa[j], 8);
    }
    if (al == 0) redv[wave][prt] = pa[0] + pa[1] + pa[2] + pa[3] + 4.f * eh_b2[0];
  }
  __syncthreads();
  if (t == 0) {
    float tot = 0.f;
#pragma unroll
    for (int w_ = 0; w_ < 2; ++w_)
#pragma unroll
      for (int p = 0; p < 4; ++p) tot += redv[w_][p];
    atomicAdd(&out[gph], tot * tanhf(far_gate[0]) * expf(energy_scale[0]));
  }
}

// ================================================================ launch
extern "C" void kernel_launch(void* const* d_in, const int* in_sizes, int n_in,
                              void* d_out, int out_size, void* d_ws, size_t ws_size,
                              hipStream_t stream) {
  const float* x         = (const float*)d_in[0];
  const float* pos       = (const float*)d_in[1];
  const float* in_ln_g   = (const float*)d_in[4];
  const float* in_ln_b   = (const float*)d_in[5];
  const float* src_w1    = (const float*)d_in[6];
  const float* src_b1    = (const float*)d_in[7];
  const float* src_w2    = (const float*)d_in[8];
  const float* src_b2    = (const float*)d_in[9];
  const float* src_ln_g  = (const float*)d_in[10];
  const float* src_ln_b  = (const float*)d_in[11];
  const float* se_ln_g   = (const float*)d_in[12];
  const float* se_ln_b   = (const float*)d_in[13];
  const float* se_w1     = (const float*)d_in[14];
  const float* se_b1     = (const float*)d_in[15];
  const float* se_w2     = (const float*)d_in[16];
  const float* se_b2     = (const float*)d_in[17];
  const float* eh_ln_g   = (const float*)d_in[18];
  const float* eh_ln_b   = (const float*)d_in[19];
  const float* eh_w1     = (const float*)d_in[20];
  const float* eh_b1     = (const float*)d_in[21];
  const float* eh_w2     = (const float*)d_in[22];
  const float* eh_b2     = (const float*)d_in[23];
  const float* k_screen  = (const float*)d_in[24];
  const float* kg_w1     = (const float*)d_in[25];
  const float* kg_b1     = (const float*)d_in[26];
  const float* kg_w2     = (const float*)d_in[27];
  const float* kg_b2     = (const float*)d_in[28];
  const float* far_gate  = (const float*)d_in[29];
  const float* en_scale  = (const float*)d_in[30];
  float* out = (float*)d_out;

  float* ws_src   = (float*)d_ws;                            // M*16
  float* ws_shell = ws_src + (size_t)M_AT * DD;              // M*95
  float* ws_part  = ws_shell + (size_t)M_AT * SEIN;          // 256*16
  float2* ws_lut  = (float2*)(ws_part + 256 * 16);           // NLUT float2

  k_front<<<260, 128, 0, stream>>>(x, in_ln_g, in_ln_b, src_w1, src_b1,
                                   src_w2, src_b2, src_ln_g, src_ln_b,
                                   k_screen, kg_w1, kg_b1, kg_w2, kg_b2,
                                   ws_src, ws_part, ws_lut, out);
  k_pairs<<<B_G * (N_A / 4), 256, 0, stream>>>(pos, ws_src, ws_lut, ws_part, ws_shell);
  k_tail<<<M_AT / 32, 128, 0, stream>>>(ws_src, ws_shell, ws_part,
                                        se_ln_g, se_ln_b, se_w1, se_b1, se_w2, se_b2,
                                        eh_ln_g, eh_ln_b, eh_w1, eh_b1, eh_w2, eh_b2,
                                        far_gate, en_scale, out);
}